// Round 1
// baseline (883.737 us; speedup 1.0000x reference)
//
#include <hip/hip_runtime.h>
#include <math.h>

// ---------------- CSR build ----------------

__global__ __launch_bounds__(256) void hist_kernel(const int* __restrict__ dst, int E,
                                                   int* __restrict__ deg) {
    int e = blockIdx.x * 256 + threadIdx.x;
    if (e < E) atomicAdd(&deg[dst[e]], 1);
}

__global__ __launch_bounds__(256) void scan_block(const int* __restrict__ in, int n,
                                                  int* __restrict__ out, int* __restrict__ bsums) {
    __shared__ int s[256];
    int t = threadIdx.x;
    int i = blockIdx.x * 256 + t;
    int v = (i < n) ? in[i] : 0;
    s[t] = v;
    __syncthreads();
#pragma unroll
    for (int o = 1; o < 256; o <<= 1) {
        int y = (t >= o) ? s[t - o] : 0;
        __syncthreads();
        s[t] += y;
        __syncthreads();
    }
    if (i < n) out[i] = s[t] - v;     // exclusive (local)
    if (t == 255) bsums[blockIdx.x] = s[255];
}

__global__ __launch_bounds__(256) void scan_sums(int* __restrict__ bsums, int nb) {
    __shared__ int s[256];
    int t = threadIdx.x;
    int v = (t < nb) ? bsums[t] : 0;
    s[t] = v;
    __syncthreads();
#pragma unroll
    for (int o = 1; o < 256; o <<= 1) {
        int y = (t >= o) ? s[t - o] : 0;
        __syncthreads();
        s[t] += y;
        __syncthreads();
    }
    if (t < nb) bsums[t] = s[t] - v;  // exclusive
}

__global__ __launch_bounds__(256) void scan_add(int* __restrict__ off, const int* __restrict__ bsums,
                                                int N, int E) {
    int i = blockIdx.x * 256 + threadIdx.x;
    if (i < N) off[i] += bsums[blockIdx.x];
    if (i == 0) off[N] = E;
}

__global__ __launch_bounds__(256) void copy_cursor(const int* __restrict__ off,
                                                   int* __restrict__ cursor, int N) {
    int i = blockIdx.x * 256 + threadIdx.x;
    if (i < N) cursor[i] = off[i];
}

__global__ __launch_bounds__(256) void scatter_kernel(const int* __restrict__ ei, int E,
                                                      int* __restrict__ cursor,
                                                      int* __restrict__ esrc) {
    int e = blockIdx.x * 256 + threadIdx.x;
    if (e < E) {
        int s = ei[e];          // src row
        int d = ei[E + e];      // dst row
        int pos = atomicAdd(&cursor[d], 1);
        esrc[pos] = s;
    }
}

// ---------------- fp32 GEMM: C[M x 256] = A[M x K] @ B[K x 256] ----------------

__global__ __launch_bounds__(256) void gemm_kernel(const float* __restrict__ A,
                                                   const float* __restrict__ B,
                                                   float* __restrict__ C, int M, int K) {
    const int BK = 16;
    __shared__ float As[BK][68];   // transposed, padded: As[k][m]
    __shared__ float Bs[BK][64];   // Bs[k][n]
    const int t = threadIdx.x;
    const int tx = t & 15, ty = t >> 4;
    const int bm = blockIdx.x * 64;
    const int bn = blockIdx.y * 64;

    const int ar = t >> 2;           // 0..63  (A row within tile)
    const int ac = (t & 3) << 2;     // 0,4,8,12 (A col group)
    const int br = t >> 4;           // 0..15  (B row within tile)
    const int bc = (t & 15) << 2;    // 0..60  (B col group)

    float acc[4][4] = {{0.f}};

    for (int k0 = 0; k0 < K; k0 += BK) {
        float4 av = make_float4(0.f, 0.f, 0.f, 0.f);
        int gr = bm + ar;
        if (gr < M) av = *(const float4*)(A + (size_t)gr * K + k0 + ac);
        As[ac + 0][ar] = av.x;
        As[ac + 1][ar] = av.y;
        As[ac + 2][ar] = av.z;
        As[ac + 3][ar] = av.w;
        float4 bv = *(const float4*)(B + (size_t)(k0 + br) * 256 + bn + bc);
        *(float4*)&Bs[br][bc] = bv;
        __syncthreads();
#pragma unroll
        for (int k = 0; k < BK; k++) {
            float4 a = *(const float4*)&As[k][ty << 2];
            float4 b = *(const float4*)&Bs[k][tx << 2];
            float aa[4] = {a.x, a.y, a.z, a.w};
            float bb[4] = {b.x, b.y, b.z, b.w};
#pragma unroll
            for (int i = 0; i < 4; i++)
#pragma unroll
                for (int j = 0; j < 4; j++)
                    acc[i][j] = fmaf(aa[i], bb[j], acc[i][j]);
        }
        __syncthreads();
    }
#pragma unroll
    for (int i = 0; i < 4; i++) {
        int gr = bm + (ty << 2) + i;
        if (gr < M) {
            float4 v = make_float4(acc[i][0], acc[i][1], acc[i][2], acc[i][3]);
            *(float4*)(C + (size_t)gr * 256 + bn + (tx << 2)) = v;
        }
    }
}

// ---------------- per-node-head attention coefficients ----------------

__global__ __launch_bounds__(256) void alpha_kernel(const float* __restrict__ h,
                                                    const float* __restrict__ a_src,
                                                    const float* __restrict__ a_dst,
                                                    float* __restrict__ aS, float* __restrict__ aD,
                                                    int N) {
    int idx = blockIdx.x * 256 + threadIdx.x;  // (node, head)
    if (idx >= N * 8) return;
    int i = idx >> 3, hd = idx & 7;
    const float4* hp = (const float4*)(h + (size_t)i * 256 + hd * 32);
    const float4* sp = (const float4*)(a_src + hd * 32);
    const float4* dp = (const float4*)(a_dst + hd * 32);
    float s = 0.f, d = 0.f;
#pragma unroll
    for (int q = 0; q < 8; q++) {
        float4 hv = hp[q], sv = sp[q], dv = dp[q];
        s += hv.x * sv.x + hv.y * sv.y + hv.z * sv.z + hv.w * sv.w;
        d += hv.x * dv.x + hv.y * dv.y + hv.z * dv.z + hv.w * dv.w;
    }
    aS[idx] = s;
    aD[idx] = d;
}

// ---------------- fused segment-softmax + aggregate + bias + ELU ----------------
// one block per dst node; thread t = (head = t>>5, c = t&31)

__global__ __launch_bounds__(256) void attn_kernel(const float* __restrict__ h,
                                                   const float* __restrict__ aS,
                                                   const float* __restrict__ aD,
                                                   const int* __restrict__ off,
                                                   const int* __restrict__ esrc,
                                                   const float* __restrict__ bias,
                                                   float* __restrict__ out, int N) {
    int i = blockIdx.x;
    int t = threadIdx.x;
    int head = t >> 5;
    int s0 = off[i], s1 = off[i + 1];
    float ad = aD[i * 8 + head];

    float m = -INFINITY;
    for (int j = s0; j < s1; j++) {
        int s = esrc[j];
        float e = aS[s * 8 + head] + ad;
        e = (e > 0.f) ? e : 0.2f * e;
        m = fmaxf(m, e);
    }
    float denom = 0.f, acc = 0.f;
    for (int j = s0; j < s1; j++) {
        int s = esrc[j];
        float e = aS[s * 8 + head] + ad;
        e = (e > 0.f) ? e : 0.2f * e;
        float p = __expf(e - m);
        denom += p;
        acc += p * h[(size_t)s * 256 + t];
    }
    float o = acc / (denom + 1e-16f);
    o += bias[t];
    o = (o > 0.f) ? o : expm1f(o);      // ELU
    out[(size_t)i * 256 + t] = o;
}

// ---------------- readout ----------------

__global__ __launch_bounds__(256) void colsum_kernel(const float* __restrict__ src, int N,
                                                     float* __restrict__ gpart) {
    int t = threadIdx.x;
    float acc = 0.f;
    for (int i = blockIdx.x; i < N; i += gridDim.x)
        acc += src[(size_t)i * 256 + t];
    atomicAdd(&gpart[t], acc);
}

__global__ __launch_bounds__(256) void final_kernel(const float* __restrict__ gpart,
                                                    const float* __restrict__ lw,
                                                    const float* __restrict__ lb,
                                                    const float* __restrict__ u,
                                                    const float* __restrict__ w,
                                                    float invN, float* __restrict__ out) {
    __shared__ float s[256];
    int t = threadIdx.x;
    s[t] = gpart[t] * invN * lw[t];
    __syncthreads();
    for (int o = 128; o > 0; o >>= 1) {
        if (t < o) s[t] += s[t + o];
        __syncthreads();
    }
    if (t == 0) out[0] = s[0] + u[0] * lw[256] + w[0] * lw[257] + lb[0];
}

// ---------------- launcher ----------------

extern "C" void kernel_launch(void* const* d_in, const int* in_sizes, int n_in,
                              void* d_out, int out_size, void* d_ws, size_t ws_size,
                              hipStream_t stream) {
    const float* x   = (const float*)d_in[0];
    const int*   ei  = (const int*)d_in[1];
    const float* u   = (const float*)d_in[2];
    const float* w   = (const float*)d_in[3];
    const float* W1  = (const float*)d_in[4];
    const float* as1 = (const float*)d_in[5];
    const float* ad1 = (const float*)d_in[6];
    const float* b1  = (const float*)d_in[7];
    const float* W2  = (const float*)d_in[8];
    const float* as2 = (const float*)d_in[9];
    const float* ad2 = (const float*)d_in[10];
    const float* b2  = (const float*)d_in[11];
    const float* lw  = (const float*)d_in[12];
    const float* lb  = (const float*)d_in[13];
    float* out = (float*)d_out;

    const int N = in_sizes[0] / 128;
    const int E = in_sizes[1] / 2;

    char* p = (char*)d_ws;
    auto alloc = [&](size_t bytes) -> char* {
        char* r = p;
        p += (bytes + 255) & ~(size_t)255;
        return r;
    };
    float* bufA  = (float*)alloc((size_t)N * 256 * 4);
    float* bufB  = (float*)alloc((size_t)N * 256 * 4);
    float* aS    = (float*)alloc((size_t)N * 8 * 4);
    float* aD    = (float*)alloc((size_t)N * 8 * 4);
    float* gpart = (float*)alloc(256 * 4);
    int* off     = (int*)alloc((size_t)(N + 1) * 4);
    int* deg     = (int*)alloc((size_t)N * 4);
    int* cursor  = (int*)alloc((size_t)N * 4);
    int* bsums   = (int*)alloc(256 * 4);
    int* esrc    = (int*)alloc((size_t)E * 4);

    hipMemsetAsync(deg, 0, (size_t)N * 4, stream);
    hipMemsetAsync(gpart, 0, 256 * 4, stream);

    const int NB = (N + 255) / 256;
    const int EB = (E + 255) / 256;

    hist_kernel<<<EB, 256, 0, stream>>>(ei + E, E, deg);
    scan_block<<<NB, 256, 0, stream>>>(deg, N, off, bsums);
    scan_sums<<<1, 256, 0, stream>>>(bsums, NB);
    scan_add<<<NB, 256, 0, stream>>>(off, bsums, N, E);
    copy_cursor<<<NB, 256, 0, stream>>>(off, cursor, N);
    scatter_kernel<<<EB, 256, 0, stream>>>(ei, E, cursor, esrc);

    dim3 ggrid((N + 63) / 64, 4);
    // layer 1
    gemm_kernel<<<ggrid, 256, 0, stream>>>(x, W1, bufA, N, 128);
    alpha_kernel<<<(N * 8 + 255) / 256, 256, 0, stream>>>(bufA, as1, ad1, aS, aD, N);
    attn_kernel<<<N, 256, 0, stream>>>(bufA, aS, aD, off, esrc, b1, bufB, N);
    // layer 2
    gemm_kernel<<<ggrid, 256, 0, stream>>>(bufB, W2, bufA, N, 256);
    alpha_kernel<<<(N * 8 + 255) / 256, 256, 0, stream>>>(bufA, as2, ad2, aS, aD, N);
    attn_kernel<<<N, 256, 0, stream>>>(bufA, aS, aD, off, esrc, b2, bufB, N);
    // readout
    colsum_kernel<<<256, 256, 0, stream>>>(bufB, N, gpart);
    final_kernel<<<1, 256, 0, stream>>>(gpart, lw, lb, u, w, 1.0f / (float)N, out);
}

// Round 2
// 543.278 us; speedup vs baseline: 1.6267x; 1.6267x over previous
//
#include <hip/hip_runtime.h>
#include <math.h>

typedef unsigned short ushort_t;

__device__ __forceinline__ unsigned short f2bf(float f) {
    unsigned u = __float_as_uint(f);
    unsigned r = (u + 0x7fffu + ((u >> 16) & 1u)) >> 16;   // RNE
    return (unsigned short)r;
}
__device__ __forceinline__ float bf2f(unsigned short b) {
    return __uint_as_float(((unsigned)b) << 16);
}

// ---------------- CSR build ----------------

__global__ __launch_bounds__(256) void hist_kernel(const int* __restrict__ dst, int E,
                                                   int* __restrict__ deg) {
    int e = blockIdx.x * 256 + threadIdx.x;
    if (e < E) atomicAdd(&deg[dst[e]], 1);
}

__global__ __launch_bounds__(256) void scan_block(const int* __restrict__ in, int n,
                                                  int* __restrict__ out, int* __restrict__ bsums) {
    __shared__ int s[256];
    int t = threadIdx.x;
    int i = blockIdx.x * 256 + t;
    int v = (i < n) ? in[i] : 0;
    s[t] = v;
    __syncthreads();
#pragma unroll
    for (int o = 1; o < 256; o <<= 1) {
        int y = (t >= o) ? s[t - o] : 0;
        __syncthreads();
        s[t] += y;
        __syncthreads();
    }
    if (i < n) out[i] = s[t] - v;
    if (t == 255) bsums[blockIdx.x] = s[255];
}

__global__ __launch_bounds__(256) void scan_sums(int* __restrict__ bsums, int nb) {
    __shared__ int s[256];
    int t = threadIdx.x;
    int v = (t < nb) ? bsums[t] : 0;
    s[t] = v;
    __syncthreads();
#pragma unroll
    for (int o = 1; o < 256; o <<= 1) {
        int y = (t >= o) ? s[t - o] : 0;
        __syncthreads();
        s[t] += y;
        __syncthreads();
    }
    if (t < nb) bsums[t] = s[t] - v;
}

__global__ __launch_bounds__(256) void scan_add(int* __restrict__ off, const int* __restrict__ bsums,
                                                int N, int E) {
    int i = blockIdx.x * 256 + threadIdx.x;
    if (i < N) off[i] += bsums[blockIdx.x];
    if (i == 0) off[N] = E;
}

__global__ __launch_bounds__(256) void copy_cursor(const int* __restrict__ off,
                                                   int* __restrict__ cursor, int N) {
    int i = blockIdx.x * 256 + threadIdx.x;
    if (i < N) cursor[i] = off[i];
}

__global__ __launch_bounds__(256) void scatter_kernel(const int* __restrict__ ei, int E,
                                                      int* __restrict__ cursor,
                                                      int* __restrict__ esrc) {
    int e = blockIdx.x * 256 + threadIdx.x;
    if (e < E) {
        int s = ei[e];
        int d = ei[E + e];
        int pos = atomicAdd(&cursor[d], 1);
        esrc[pos] = s;
    }
}

// ---------------- fp32 GEMM with fused bf16 mirror: C[Mx256]=A[MxK]@B[Kx256] ----------------

__global__ __launch_bounds__(256) void gemm_kernel(const float* __restrict__ A,
                                                   const float* __restrict__ B,
                                                   float* __restrict__ C,
                                                   ushort_t* __restrict__ Cb,
                                                   int M, int K) {
    const int BK = 16;
    __shared__ float As[BK][68];
    __shared__ float Bs[BK][64];
    const int t = threadIdx.x;
    const int tx = t & 15, ty = t >> 4;
    const int bm = blockIdx.x * 64;
    const int bn = blockIdx.y * 64;

    const int ar = t >> 2;
    const int ac = (t & 3) << 2;
    const int br = t >> 4;
    const int bc = (t & 15) << 2;

    float acc[4][4] = {{0.f}};

    for (int k0 = 0; k0 < K; k0 += BK) {
        float4 av = make_float4(0.f, 0.f, 0.f, 0.f);
        int gr = bm + ar;
        if (gr < M) av = *(const float4*)(A + (size_t)gr * K + k0 + ac);
        As[ac + 0][ar] = av.x;
        As[ac + 1][ar] = av.y;
        As[ac + 2][ar] = av.z;
        As[ac + 3][ar] = av.w;
        float4 bv = *(const float4*)(B + (size_t)(k0 + br) * 256 + bn + bc);
        *(float4*)&Bs[br][bc] = bv;
        __syncthreads();
#pragma unroll
        for (int k = 0; k < BK; k++) {
            float4 a = *(const float4*)&As[k][ty << 2];
            float4 b = *(const float4*)&Bs[k][tx << 2];
            float aa[4] = {a.x, a.y, a.z, a.w};
            float bb[4] = {b.x, b.y, b.z, b.w};
#pragma unroll
            for (int i = 0; i < 4; i++)
#pragma unroll
                for (int j = 0; j < 4; j++)
                    acc[i][j] = fmaf(aa[i], bb[j], acc[i][j]);
        }
        __syncthreads();
    }
#pragma unroll
    for (int i = 0; i < 4; i++) {
        int gr = bm + (ty << 2) + i;
        if (gr < M) {
            float4 v = make_float4(acc[i][0], acc[i][1], acc[i][2], acc[i][3]);
            *(float4*)(C + (size_t)gr * 256 + bn + (tx << 2)) = v;
            ushort4 q;
            q.x = f2bf(v.x); q.y = f2bf(v.y); q.z = f2bf(v.z); q.w = f2bf(v.w);
            *(ushort4*)(Cb + (size_t)gr * 256 + bn + (tx << 2)) = q;
        }
    }
}

// ---------------- per-node-head attention coefficients ----------------

__global__ __launch_bounds__(256) void alpha_kernel(const float* __restrict__ h,
                                                    const float* __restrict__ a_src,
                                                    const float* __restrict__ a_dst,
                                                    float* __restrict__ aS, float* __restrict__ aD,
                                                    int N) {
    int idx = blockIdx.x * 256 + threadIdx.x;
    if (idx >= N * 8) return;
    int i = idx >> 3, hd = idx & 7;
    const float4* hp = (const float4*)(h + (size_t)i * 256 + hd * 32);
    const float4* sp = (const float4*)(a_src + hd * 32);
    const float4* dp = (const float4*)(a_dst + hd * 32);
    float s = 0.f, d = 0.f;
#pragma unroll
    for (int q = 0; q < 8; q++) {
        float4 hv = hp[q], sv = sp[q], dv = dp[q];
        s += hv.x * sv.x + hv.y * sv.y + hv.z * sv.z + hv.w * sv.w;
        d += hv.x * dv.x + hv.y * dv.y + hv.z * dv.z + hv.w * dv.w;
    }
    aS[idx] = s;
    aD[idx] = d;
}

// ---------------- per-node segment softmax -> per-edge normalized alpha ----------------
// 4 waves/block, 1 wave per node. lane: head = lane&7, edge-slot = lane>>3.

__global__ __launch_bounds__(256) void softmax_kernel(const float* __restrict__ aS,
                                                      const float* __restrict__ aD,
                                                      const int* __restrict__ off,
                                                      const int* __restrict__ esrc,
                                                      float* __restrict__ alpha, int N) {
    int lane = threadIdx.x & 63;
    int node = blockIdx.x * 4 + (threadIdx.x >> 6);
    if (node >= N) return;
    int head = lane & 7, k0 = lane >> 3;
    int s0 = off[node], s1 = off[node + 1];
    float ad = aD[node * 8 + head];

    float m = -INFINITY;
    for (int j = s0 + k0; j < s1; j += 8) {
        float e = aS[(size_t)esrc[j] * 8 + head] + ad;
        e = (e > 0.f) ? e : 0.2f * e;
        m = fmaxf(m, e);
    }
    m = fmaxf(m, __shfl_xor(m, 8));
    m = fmaxf(m, __shfl_xor(m, 16));
    m = fmaxf(m, __shfl_xor(m, 32));

    float dsum = 0.f;
    for (int j = s0 + k0; j < s1; j += 8) {
        float e = aS[(size_t)esrc[j] * 8 + head] + ad;
        e = (e > 0.f) ? e : 0.2f * e;
        dsum += __expf(e - m);
    }
    dsum += __shfl_xor(dsum, 8);
    dsum += __shfl_xor(dsum, 16);
    dsum += __shfl_xor(dsum, 32);
    float inv = 1.f / (dsum + 1e-16f);

    for (int j = s0 + k0; j < s1; j += 8) {
        float e = aS[(size_t)esrc[j] * 8 + head] + ad;
        e = (e > 0.f) ? e : 0.2f * e;
        alpha[(size_t)j * 8 + head] = __expf(e - m) * inv;
    }
}

// ---------------- single-pass weighted bf16 gather + bias + ELU ----------------
// 4 waves/block, 1 wave per node. lane: head = lane>>3 (8 lanes/head), 4 channels each.

__global__ __launch_bounds__(256) void aggregate_kernel(const ushort_t* __restrict__ hb,
                                                        const float* __restrict__ alpha,
                                                        const int* __restrict__ off,
                                                        const int* __restrict__ esrc,
                                                        const float* __restrict__ bias,
                                                        float* __restrict__ out, int N) {
    int lane = threadIdx.x & 63;
    int node = blockIdx.x * 4 + (threadIdx.x >> 6);
    if (node >= N) return;
    int head = lane >> 3;
    int col = head * 32 + ((lane & 7) << 2);   // 4 consecutive channels
    int s0 = off[node], s1 = off[node + 1];

    float acc0 = 0.f, acc1 = 0.f, acc2 = 0.f, acc3 = 0.f;
    int j = s0;
    for (; j + 2 <= s1; j += 2) {
        int sA = esrc[j], sB = esrc[j + 1];
        float aA = alpha[(size_t)j * 8 + head];
        float aB = alpha[(size_t)(j + 1) * 8 + head];
        ushort4 hA = *(const ushort4*)(hb + (size_t)sA * 256 + col);
        ushort4 hB = *(const ushort4*)(hb + (size_t)sB * 256 + col);
        acc0 = fmaf(aA, bf2f(hA.x), acc0);
        acc1 = fmaf(aA, bf2f(hA.y), acc1);
        acc2 = fmaf(aA, bf2f(hA.z), acc2);
        acc3 = fmaf(aA, bf2f(hA.w), acc3);
        acc0 = fmaf(aB, bf2f(hB.x), acc0);
        acc1 = fmaf(aB, bf2f(hB.y), acc1);
        acc2 = fmaf(aB, bf2f(hB.z), acc2);
        acc3 = fmaf(aB, bf2f(hB.w), acc3);
    }
    for (; j < s1; ++j) {
        int s = esrc[j];
        float a = alpha[(size_t)j * 8 + head];
        ushort4 hv = *(const ushort4*)(hb + (size_t)s * 256 + col);
        acc0 = fmaf(a, bf2f(hv.x), acc0);
        acc1 = fmaf(a, bf2f(hv.y), acc1);
        acc2 = fmaf(a, bf2f(hv.z), acc2);
        acc3 = fmaf(a, bf2f(hv.w), acc3);
    }
    float4 bv = *(const float4*)(bias + col);
    float o0 = acc0 + bv.x, o1 = acc1 + bv.y, o2 = acc2 + bv.z, o3 = acc3 + bv.w;
    o0 = (o0 > 0.f) ? o0 : expm1f(o0);
    o1 = (o1 > 0.f) ? o1 : expm1f(o1);
    o2 = (o2 > 0.f) ? o2 : expm1f(o2);
    o3 = (o3 > 0.f) ? o3 : expm1f(o3);
    *(float4*)(out + (size_t)node * 256 + col) = make_float4(o0, o1, o2, o3);
}

// ---------------- readout ----------------

__global__ __launch_bounds__(256) void colsum_kernel(const float* __restrict__ src, int N,
                                                     float* __restrict__ gpart) {
    int t = threadIdx.x;
    float acc = 0.f;
    for (int i = blockIdx.x; i < N; i += gridDim.x)
        acc += src[(size_t)i * 256 + t];
    atomicAdd(&gpart[t], acc);
}

__global__ __launch_bounds__(256) void final_kernel(const float* __restrict__ gpart,
                                                    const float* __restrict__ lw,
                                                    const float* __restrict__ lb,
                                                    const float* __restrict__ u,
                                                    const float* __restrict__ w,
                                                    float invN, float* __restrict__ out) {
    __shared__ float s[256];
    int t = threadIdx.x;
    s[t] = gpart[t] * invN * lw[t];
    __syncthreads();
    for (int o = 128; o > 0; o >>= 1) {
        if (t < o) s[t] += s[t + o];
        __syncthreads();
    }
    if (t == 0) out[0] = s[0] + u[0] * lw[256] + w[0] * lw[257] + lb[0];
}

// ---------------- launcher ----------------

extern "C" void kernel_launch(void* const* d_in, const int* in_sizes, int n_in,
                              void* d_out, int out_size, void* d_ws, size_t ws_size,
                              hipStream_t stream) {
    const float* x   = (const float*)d_in[0];
    const int*   ei  = (const int*)d_in[1];
    const float* u   = (const float*)d_in[2];
    const float* w   = (const float*)d_in[3];
    const float* W1  = (const float*)d_in[4];
    const float* as1 = (const float*)d_in[5];
    const float* ad1 = (const float*)d_in[6];
    const float* b1  = (const float*)d_in[7];
    const float* W2  = (const float*)d_in[8];
    const float* as2 = (const float*)d_in[9];
    const float* ad2 = (const float*)d_in[10];
    const float* b2  = (const float*)d_in[11];
    const float* lw  = (const float*)d_in[12];
    const float* lb  = (const float*)d_in[13];
    float* out = (float*)d_out;

    const int N = in_sizes[0] / 128;
    const int E = in_sizes[1] / 2;

    char* p = (char*)d_ws;
    auto alloc = [&](size_t bytes) -> char* {
        char* r = p;
        p += (bytes + 255) & ~(size_t)255;
        return r;
    };
    float* bufA  = (float*)alloc((size_t)N * 256 * 4);   // fp32 h; lower 25.6MB reused for alpha
    float* bufB  = (float*)alloc((size_t)N * 256 * 4);
    ushort_t* hb = (ushort_t*)alloc((size_t)N * 256 * 2);
    float* aS    = (float*)alloc((size_t)N * 8 * 4);
    float* aD    = (float*)alloc((size_t)N * 8 * 4);
    float* gpart = (float*)alloc(256 * 4);
    int* off     = (int*)alloc((size_t)(N + 1) * 4);
    int* deg     = (int*)alloc((size_t)N * 4);
    int* cursor  = (int*)alloc((size_t)N * 4);
    int* bsums   = (int*)alloc(256 * 4);
    int* esrc    = (int*)alloc((size_t)E * 4);

    float* alphaBuf = bufA;   // alias: fp32 h is dead once aS/aD are computed

    hipMemsetAsync(deg, 0, (size_t)N * 4, stream);
    hipMemsetAsync(gpart, 0, 256 * 4, stream);

    const int NB = (N + 255) / 256;
    const int EB = (E + 255) / 256;
    const int N4 = (N + 3) / 4;

    hist_kernel<<<EB, 256, 0, stream>>>(ei + E, E, deg);
    scan_block<<<NB, 256, 0, stream>>>(deg, N, off, bsums);
    scan_sums<<<1, 256, 0, stream>>>(bsums, NB);
    scan_add<<<NB, 256, 0, stream>>>(off, bsums, N, E);
    copy_cursor<<<NB, 256, 0, stream>>>(off, cursor, N);
    scatter_kernel<<<EB, 256, 0, stream>>>(ei, E, cursor, esrc);

    dim3 ggrid((N + 63) / 64, 4);
    // layer 1
    gemm_kernel<<<ggrid, 256, 0, stream>>>(x, W1, bufA, hb, N, 128);
    alpha_kernel<<<(N * 8 + 255) / 256, 256, 0, stream>>>(bufA, as1, ad1, aS, aD, N);
    softmax_kernel<<<N4, 256, 0, stream>>>(aS, aD, off, esrc, alphaBuf, N);
    aggregate_kernel<<<N4, 256, 0, stream>>>(hb, alphaBuf, off, esrc, b1, bufB, N);
    // layer 2
    gemm_kernel<<<ggrid, 256, 0, stream>>>(bufB, W2, bufA, hb, N, 256);
    alpha_kernel<<<(N * 8 + 255) / 256, 256, 0, stream>>>(bufA, as2, ad2, aS, aD, N);
    softmax_kernel<<<N4, 256, 0, stream>>>(aS, aD, off, esrc, alphaBuf, N);
    aggregate_kernel<<<N4, 256, 0, stream>>>(hb, alphaBuf, off, esrc, b2, bufB, N);
    // readout
    colsum_kernel<<<256, 256, 0, stream>>>(bufB, N, gpart);
    final_kernel<<<1, 256, 0, stream>>>(gpart, lw, lb, u, w, 1.0f / (float)N, out);
}

// Round 3
// 424.084 us; speedup vs baseline: 2.0839x; 1.2811x over previous
//
#include <hip/hip_runtime.h>
#include <math.h>

typedef unsigned short ushort_t;
typedef __attribute__((ext_vector_type(8))) short short8;
typedef __attribute__((ext_vector_type(4))) float f32x4;

__device__ __forceinline__ unsigned short f2bf(float f) {
    unsigned u = __float_as_uint(f);
    unsigned r = (u + 0x7fffu + ((u >> 16) & 1u)) >> 16;   // RNE
    return (unsigned short)r;
}
__device__ __forceinline__ float bf2f(unsigned short b) {
    return __uint_as_float(((unsigned)b) << 16);
}

__device__ __forceinline__ void gld_lds16(const ushort_t* g, ushort_t* l) {
    __builtin_amdgcn_global_load_lds(
        (const __attribute__((address_space(1))) unsigned int*)g,
        (__attribute__((address_space(3))) unsigned int*)l,
        16, 0, 0);
}

// ---------------- small converts ----------------

__global__ __launch_bounds__(256) void convert_bf16_kernel(const float* __restrict__ in,
                                                           ushort_t* __restrict__ out, int n4) {
    int i = blockIdx.x * 256 + threadIdx.x;
    if (i < n4) {
        float4 v = *(const float4*)(in + (size_t)i * 4);
        ushort4 q;
        q.x = f2bf(v.x); q.y = f2bf(v.y); q.z = f2bf(v.z); q.w = f2bf(v.w);
        *(ushort4*)(out + (size_t)i * 4) = q;
    }
}

// W[K][256] -> Wt[256][K] bf16
__global__ __launch_bounds__(256) void transpose_w_kernel(const float* __restrict__ W,
                                                          ushort_t* __restrict__ Wt, int K) {
    int idx = blockIdx.x * 256 + threadIdx.x;
    if (idx < K * 256) {
        int k = idx >> 8, n = idx & 255;
        Wt[(size_t)n * K + k] = f2bf(W[idx]);
    }
}

// ---------------- CSR build ----------------

__global__ __launch_bounds__(256) void hist_kernel(const int* __restrict__ dst, int E,
                                                   int* __restrict__ deg) {
    int e = blockIdx.x * 256 + threadIdx.x;
    if (e < E) atomicAdd(&deg[dst[e]], 1);
}

__global__ __launch_bounds__(256) void scan_block(const int* __restrict__ in, int n,
                                                  int* __restrict__ out, int* __restrict__ bsums) {
    __shared__ int s[256];
    int t = threadIdx.x;
    int i = blockIdx.x * 256 + t;
    int v = (i < n) ? in[i] : 0;
    s[t] = v;
    __syncthreads();
#pragma unroll
    for (int o = 1; o < 256; o <<= 1) {
        int y = (t >= o) ? s[t - o] : 0;
        __syncthreads();
        s[t] += y;
        __syncthreads();
    }
    if (i < n) out[i] = s[t] - v;
    if (t == 255) bsums[blockIdx.x] = s[255];
}

__global__ __launch_bounds__(256) void scan_sums(int* __restrict__ bsums, int nb) {
    __shared__ int s[256];
    int t = threadIdx.x;
    int v = (t < nb) ? bsums[t] : 0;
    s[t] = v;
    __syncthreads();
#pragma unroll
    for (int o = 1; o < 256; o <<= 1) {
        int y = (t >= o) ? s[t - o] : 0;
        __syncthreads();
        s[t] += y;
        __syncthreads();
    }
    if (t < nb) bsums[t] = s[t] - v;
}

__global__ __launch_bounds__(256) void scan_add(int* __restrict__ off, const int* __restrict__ bsums,
                                                int N, int E) {
    int i = blockIdx.x * 256 + threadIdx.x;
    if (i < N) off[i] += bsums[blockIdx.x];
    if (i == 0) off[N] = E;
}

__global__ __launch_bounds__(256) void copy_cursor(const int* __restrict__ off,
                                                   int* __restrict__ cursor, int N) {
    int i = blockIdx.x * 256 + threadIdx.x;
    if (i < N) cursor[i] = off[i];
}

__global__ __launch_bounds__(256) void scatter_kernel(const int* __restrict__ ei, int E,
                                                      int* __restrict__ cursor,
                                                      int* __restrict__ esrc) {
    int e = blockIdx.x * 256 + threadIdx.x;
    if (e < E) {
        int s = ei[e];
        int d = ei[E + e];
        int pos = atomicAdd(&cursor[d], 1);
        esrc[pos] = s;
    }
}

// ---------------- bf16 MFMA GEMM: C[Mx256] = A[MxK] @ Bt[256xK]^T ----------------
// 128x128 tile, BK=32, 4 waves of 64x64. Swizzled LDS (XOR slot) staged via
// global_load_lds with pre-swizzled global source (linear LDS dest).

__device__ __forceinline__ int swz4(int r) { return (r ^ (r >> 2)) & 3; }

__global__ __launch_bounds__(256) void gemm_mfma(const ushort_t* __restrict__ A,
                                                 const ushort_t* __restrict__ Bt,
                                                 ushort_t* __restrict__ C, int M, int K) {
    __shared__ ushort_t As[128 * 32];   // row-major [128][32], 64B rows
    __shared__ ushort_t Bs[128 * 32];
    const int tid = threadIdx.x;
    const int lane = tid & 63;
    const int wave = tid >> 6;
    const int bm = blockIdx.x * 128;
    const int bn = blockIdx.y * 128;
    const int wr = (wave >> 1) * 64;
    const int wc = (wave & 1) * 64;

    // staging: wave handles LDS groups G0,G1 (16 rows x 32 cols = 1KB each)
    const int G0 = wave * 2, G1 = wave * 2 + 1;
    const int rl = lane >> 2;            // row within 16-row group
    const int sl = lane & 3;             // linear 16B slot
    const int RA0 = G0 * 16 + rl, RA1 = G1 * 16 + rl;
    const int sA0 = sl ^ swz4(RA0), sA1 = sl ^ swz4(RA1);
    const int gA0 = min(bm + RA0, M - 1);
    const int gA1 = min(bm + RA1, M - 1);
    const ushort_t* srcA0 = A + (size_t)gA0 * K + sA0 * 8;
    const ushort_t* srcA1 = A + (size_t)gA1 * K + sA1 * 8;
    const ushort_t* srcB0 = Bt + (size_t)(bn + RA0) * K + sA0 * 8;
    const ushort_t* srcB1 = Bt + (size_t)(bn + RA1) * K + sA1 * 8;
    ushort_t* dA0 = &As[G0 * 512];
    ushort_t* dA1 = &As[G1 * 512];
    ushort_t* dB0 = &Bs[G0 * 512];
    ushort_t* dB1 = &Bs[G1 * 512];

    // fragment read offsets (ushort units), loop-invariant
    int offA[4], offB[4];
    const int c = lane >> 4;             // k-chunk 0..3
    const int fr = lane & 15;
#pragma unroll
    for (int mi = 0; mi < 4; mi++) {
        int r = wr + mi * 16 + fr;
        offA[mi] = r * 32 + (c ^ swz4(r)) * 8;
    }
#pragma unroll
    for (int ni = 0; ni < 4; ni++) {
        int r = wc + ni * 16 + fr;
        offB[ni] = r * 32 + (c ^ swz4(r)) * 8;
    }

    f32x4 acc[4][4];
#pragma unroll
    for (int i = 0; i < 4; i++)
#pragma unroll
        for (int j = 0; j < 4; j++)
            acc[i][j] = (f32x4){0.f, 0.f, 0.f, 0.f};

    const int nk = K >> 5;
    // prologue stage k=0
    gld_lds16(srcA0, dA0);
    gld_lds16(srcA1, dA1);
    gld_lds16(srcB0, dB0);
    gld_lds16(srcB1, dB1);

    for (int kk = 0; kk < nk; kk++) {
        __syncthreads();                 // drains vmcnt: staged tile ready
        short8 af[4], bf[4];
#pragma unroll
        for (int mi = 0; mi < 4; mi++) af[mi] = *(const short8*)&As[offA[mi]];
#pragma unroll
        for (int ni = 0; ni < 4; ni++) bf[ni] = *(const short8*)&Bs[offB[ni]];
#pragma unroll
        for (int mi = 0; mi < 4; mi++)
#pragma unroll
            for (int ni = 0; ni < 4; ni++)
                acc[mi][ni] = __builtin_amdgcn_mfma_f32_16x16x32_bf16(af[mi], bf[ni],
                                                                      acc[mi][ni], 0, 0, 0);
        __syncthreads();                 // all waves done reading before overwrite
        if (kk + 1 < nk) {
            int k0 = (kk + 1) * 32;
            gld_lds16(srcA0 + k0, dA0);
            gld_lds16(srcA1 + k0, dA1);
            gld_lds16(srcB0 + k0, dB0);
            gld_lds16(srcB1 + k0, dB1);
        }
    }

    // epilogue: C/D layout col=lane&15, row=(lane>>4)*4+j
    const int rq = (lane >> 4) * 4;
#pragma unroll
    for (int mi = 0; mi < 4; mi++) {
#pragma unroll
        for (int j = 0; j < 4; j++) {
            int row = bm + wr + mi * 16 + rq + j;
            if (row < M) {
#pragma unroll
                for (int ni = 0; ni < 4; ni++) {
                    int col = bn + wc + ni * 16 + fr;
                    C[(size_t)row * 256 + col] = f2bf(acc[mi][ni][j]);
                }
            }
        }
    }
}

// ---------------- per-node-head attention coefficients (bf16 h) ----------------

__global__ __launch_bounds__(256) void alpha_kernel(const ushort_t* __restrict__ hb,
                                                    const float* __restrict__ a_src,
                                                    const float* __restrict__ a_dst,
                                                    float* __restrict__ aS, float* __restrict__ aD,
                                                    int N) {
    int idx = blockIdx.x * 256 + threadIdx.x;
    if (idx >= N * 8) return;
    int i = idx >> 3, hd = idx & 7;
    const uint4* hp = (const uint4*)(hb + (size_t)i * 256 + hd * 32);
    const float4* sp = (const float4*)(a_src + hd * 32);
    const float4* dp = (const float4*)(a_dst + hd * 32);
    float s = 0.f, d = 0.f;
#pragma unroll
    for (int q = 0; q < 4; q++) {
        uint4 hv = hp[q];
        unsigned uu[4] = {hv.x, hv.y, hv.z, hv.w};
#pragma unroll
        for (int p = 0; p < 4; p++) {
            float h0 = __uint_as_float(uu[p] << 16);
            float h1 = __uint_as_float(uu[p] & 0xffff0000u);
            float4 sv = sp[q * 2 + (p >> 1)];
            float4 dv = dp[q * 2 + (p >> 1)];
            float s0 = (p & 1) ? sv.z : sv.x;
            float s1 = (p & 1) ? sv.w : sv.y;
            float d0 = (p & 1) ? dv.z : dv.x;
            float d1 = (p & 1) ? dv.w : dv.y;
            s += h0 * s0 + h1 * s1;
            d += h0 * d0 + h1 * d1;
        }
    }
    aS[idx] = s;
    aD[idx] = d;
}

// ---------------- per-node segment softmax -> per-edge bf16 alpha ----------------

__global__ __launch_bounds__(256) void softmax_kernel(const float* __restrict__ aS,
                                                      const float* __restrict__ aD,
                                                      const int* __restrict__ off,
                                                      const int* __restrict__ esrc,
                                                      ushort_t* __restrict__ alphaB, int N) {
    int lane = threadIdx.x & 63;
    int node = blockIdx.x * 4 + (threadIdx.x >> 6);
    if (node >= N) return;
    int head = lane & 7, k0 = lane >> 3;
    int s0 = off[node], s1 = off[node + 1];
    float ad = aD[node * 8 + head];

    float m = -INFINITY;
    for (int j = s0 + k0; j < s1; j += 8) {
        float e = aS[(size_t)esrc[j] * 8 + head] + ad;
        e = (e > 0.f) ? e : 0.2f * e;
        m = fmaxf(m, e);
    }
    m = fmaxf(m, __shfl_xor(m, 8));
    m = fmaxf(m, __shfl_xor(m, 16));
    m = fmaxf(m, __shfl_xor(m, 32));

    float dsum = 0.f;
    for (int j = s0 + k0; j < s1; j += 8) {
        float e = aS[(size_t)esrc[j] * 8 + head] + ad;
        e = (e > 0.f) ? e : 0.2f * e;
        dsum += __expf(e - m);
    }
    dsum += __shfl_xor(dsum, 8);
    dsum += __shfl_xor(dsum, 16);
    dsum += __shfl_xor(dsum, 32);
    float inv = 1.f / (dsum + 1e-16f);

    for (int j = s0 + k0; j < s1; j += 8) {
        float e = aS[(size_t)esrc[j] * 8 + head] + ad;
        e = (e > 0.f) ? e : 0.2f * e;
        alphaB[(size_t)j * 8 + head] = f2bf(__expf(e - m) * inv);
    }
}

// ---------------- weighted bf16 gather + bias + ELU -> bf16 out ----------------

__global__ __launch_bounds__(256) void aggregate_kernel(const ushort_t* __restrict__ hb,
                                                        const ushort_t* __restrict__ alphaB,
                                                        const int* __restrict__ off,
                                                        const int* __restrict__ esrc,
                                                        const float* __restrict__ bias,
                                                        ushort_t* __restrict__ out, int N) {
    int lane = threadIdx.x & 63;
    int node = blockIdx.x * 4 + (threadIdx.x >> 6);
    if (node >= N) return;
    int head = lane >> 3;
    int col = head * 32 + ((lane & 7) << 2);
    int s0 = off[node], s1 = off[node + 1];

    float acc0 = 0.f, acc1 = 0.f, acc2 = 0.f, acc3 = 0.f;
    int j = s0;
    for (; j + 2 <= s1; j += 2) {
        int sA = esrc[j], sB = esrc[j + 1];
        float aA = bf2f(alphaB[(size_t)j * 8 + head]);
        float aB = bf2f(alphaB[(size_t)(j + 1) * 8 + head]);
        ushort4 hA = *(const ushort4*)(hb + (size_t)sA * 256 + col);
        ushort4 hB = *(const ushort4*)(hb + (size_t)sB * 256 + col);
        acc0 = fmaf(aA, bf2f(hA.x), acc0);
        acc1 = fmaf(aA, bf2f(hA.y), acc1);
        acc2 = fmaf(aA, bf2f(hA.z), acc2);
        acc3 = fmaf(aA, bf2f(hA.w), acc3);
        acc0 = fmaf(aB, bf2f(hB.x), acc0);
        acc1 = fmaf(aB, bf2f(hB.y), acc1);
        acc2 = fmaf(aB, bf2f(hB.z), acc2);
        acc3 = fmaf(aB, bf2f(hB.w), acc3);
    }
    for (; j < s1; ++j) {
        int s = esrc[j];
        float a = bf2f(alphaB[(size_t)j * 8 + head]);
        ushort4 hv = *(const ushort4*)(hb + (size_t)s * 256 + col);
        acc0 = fmaf(a, bf2f(hv.x), acc0);
        acc1 = fmaf(a, bf2f(hv.y), acc1);
        acc2 = fmaf(a, bf2f(hv.z), acc2);
        acc3 = fmaf(a, bf2f(hv.w), acc3);
    }
    float4 bv = *(const float4*)(bias + col);
    float o0 = acc0 + bv.x, o1 = acc1 + bv.y, o2 = acc2 + bv.z, o3 = acc3 + bv.w;
    o0 = (o0 > 0.f) ? o0 : expm1f(o0);
    o1 = (o1 > 0.f) ? o1 : expm1f(o1);
    o2 = (o2 > 0.f) ? o2 : expm1f(o2);
    o3 = (o3 > 0.f) ? o3 : expm1f(o3);
    ushort4 q;
    q.x = f2bf(o0); q.y = f2bf(o1); q.z = f2bf(o2); q.w = f2bf(o3);
    *(ushort4*)(out + (size_t)node * 256 + col) = q;
}

// ---------------- readout ----------------

__global__ __launch_bounds__(256) void colsum_kernel(const ushort_t* __restrict__ src, int N,
                                                     float* __restrict__ gpart) {
    int t = threadIdx.x;
    float acc = 0.f;
    for (int i = blockIdx.x; i < N; i += gridDim.x)
        acc += bf2f(src[(size_t)i * 256 + t]);
    atomicAdd(&gpart[t], acc);
}

__global__ __launch_bounds__(256) void final_kernel(const float* __restrict__ gpart,
                                                    const float* __restrict__ lw,
                                                    const float* __restrict__ lb,
                                                    const float* __restrict__ u,
                                                    const float* __restrict__ w,
                                                    float invN, float* __restrict__ out) {
    __shared__ float s[256];
    int t = threadIdx.x;
    s[t] = gpart[t] * invN * lw[t];
    __syncthreads();
    for (int o = 128; o > 0; o >>= 1) {
        if (t < o) s[t] += s[t + o];
        __syncthreads();
    }
    if (t == 0) out[0] = s[0] + u[0] * lw[256] + w[0] * lw[257] + lb[0];
}

// ---------------- launcher ----------------

extern "C" void kernel_launch(void* const* d_in, const int* in_sizes, int n_in,
                              void* d_out, int out_size, void* d_ws, size_t ws_size,
                              hipStream_t stream) {
    const float* x   = (const float*)d_in[0];
    const int*   ei  = (const int*)d_in[1];
    const float* u   = (const float*)d_in[2];
    const float* w   = (const float*)d_in[3];
    const float* W1  = (const float*)d_in[4];
    const float* as1 = (const float*)d_in[5];
    const float* ad1 = (const float*)d_in[6];
    const float* b1  = (const float*)d_in[7];
    const float* W2  = (const float*)d_in[8];
    const float* as2 = (const float*)d_in[9];
    const float* ad2 = (const float*)d_in[10];
    const float* b2  = (const float*)d_in[11];
    const float* lw  = (const float*)d_in[12];
    const float* lb  = (const float*)d_in[13];
    float* out = (float*)d_out;

    const int N = in_sizes[0] / 128;
    const int E = in_sizes[1] / 2;

    char* p = (char*)d_ws;
    auto alloc = [&](size_t bytes) -> char* {
        char* r = p;
        p += (bytes + 255) & ~(size_t)255;
        return r;
    };
    ushort_t* xb   = (ushort_t*)alloc((size_t)N * 128 * 2);
    ushort_t* hb   = (ushort_t*)alloc((size_t)N * 256 * 2);
    ushort_t* outb = (ushort_t*)alloc((size_t)N * 256 * 2);
    ushort_t* w1t  = (ushort_t*)alloc((size_t)256 * 128 * 2);
    ushort_t* w2t  = (ushort_t*)alloc((size_t)256 * 256 * 2);
    ushort_t* alB  = (ushort_t*)alloc((size_t)E * 8 * 2);
    float* aS    = (float*)alloc((size_t)N * 8 * 4);
    float* aD    = (float*)alloc((size_t)N * 8 * 4);
    float* gpart = (float*)alloc(256 * 4);
    int* off     = (int*)alloc((size_t)(N + 1) * 4);
    int* deg     = (int*)alloc((size_t)N * 4);
    int* cursor  = (int*)alloc((size_t)N * 4);
    int* bsums   = (int*)alloc(256 * 4);
    int* esrc    = (int*)alloc((size_t)E * 4);

    hipMemsetAsync(deg, 0, (size_t)N * 4, stream);
    hipMemsetAsync(gpart, 0, 256 * 4, stream);

    const int NB = (N + 255) / 256;
    const int EB = (E + 255) / 256;
    const int N4 = (N + 3) / 4;

    // converts + CSR build
    convert_bf16_kernel<<<(N * 128 / 4 + 255) / 256, 256, 0, stream>>>(x, xb, N * 128 / 4);
    transpose_w_kernel<<<128, 256, 0, stream>>>(W1, w1t, 128);
    transpose_w_kernel<<<256, 256, 0, stream>>>(W2, w2t, 256);
    hist_kernel<<<EB, 256, 0, stream>>>(ei + E, E, deg);
    scan_block<<<NB, 256, 0, stream>>>(deg, N, off, bsums);
    scan_sums<<<1, 256, 0, stream>>>(bsums, NB);
    scan_add<<<NB, 256, 0, stream>>>(off, bsums, N, E);
    copy_cursor<<<NB, 256, 0, stream>>>(off, cursor, N);
    scatter_kernel<<<EB, 256, 0, stream>>>(ei, E, cursor, esrc);

    dim3 ggrid((N + 127) / 128, 2);
    // layer 1
    gemm_mfma<<<ggrid, 256, 0, stream>>>(xb, w1t, hb, N, 128);
    alpha_kernel<<<(N * 8 + 255) / 256, 256, 0, stream>>>(hb, as1, ad1, aS, aD, N);
    softmax_kernel<<<N4, 256, 0, stream>>>(aS, aD, off, esrc, alB, N);
    aggregate_kernel<<<N4, 256, 0, stream>>>(hb, alB, off, esrc, b1, outb, N);
    // layer 2
    gemm_mfma<<<ggrid, 256, 0, stream>>>(outb, w2t, hb, N, 256);
    alpha_kernel<<<(N * 8 + 255) / 256, 256, 0, stream>>>(hb, as2, ad2, aS, aD, N);
    softmax_kernel<<<N4, 256, 0, stream>>>(aS, aD, off, esrc, alB, N);
    aggregate_kernel<<<N4, 256, 0, stream>>>(hb, alB, off, esrc, b2, outb, N);
    // readout
    colsum_kernel<<<256, 256, 0, stream>>>(outb, N, gpart);
    final_kernel<<<1, 256, 0, stream>>>(gpart, lw, lb, u, w, 1.0f / (float)N, out);
}